// Round 1
// 328.013 us; speedup vs baseline: 1.1091x; 1.1091x over previous
//
#include <hip/hip_runtime.h>
#include <hip/hip_bf16.h>
#include <math.h>

#define NB 16
#define SS 64
#define HH 256
#define FAA 256

using short8 = __attribute__((ext_vector_type(8))) short;
using f32x4  = __attribute__((ext_vector_type(4))) float;

__device__ __forceinline__ float bf2f_u(unsigned int u) {
  union { unsigned int u; float f; } x; x.u = u << 16; return x.f;
}
__device__ __forceinline__ unsigned short f2bf(float f) {
  union { float f; unsigned int u; } x; x.f = f;
  unsigned int u = x.u;
  return (unsigned short)((u + 0x7FFFu + ((u >> 16) & 1u)) >> 16);  // RNE
}
__device__ __forceinline__ unsigned int pk2(float a, float b) {
  return (unsigned int)f2bf(a) | ((unsigned int)f2bf(b) << 16);
}

// ---------------------------------------------------------------------------
// Prolog: fp32 -> bf16 conversions of weights / reused activations.
// wcat layout: rows 0..255 = Ur[o][k], rows 256..511 = U[o-256][k] (row-major K=256)
// ---------------------------------------------------------------------------
__global__ void prolog_cvt(const float* __restrict__ z1w, const float* __restrict__ Ur,
                           const float* __restrict__ U, const float* __restrict__ nmw,
                           const float* __restrict__ pm, const float* __restrict__ qs,
                           unsigned short* __restrict__ z1wbf, unsigned short* __restrict__ wcatbf,
                           unsigned short* __restrict__ nmbf, unsigned short* __restrict__ pmbf,
                           unsigned short* __restrict__ qbf) {
  int idx = blockIdx.x * 256 + threadIdx.x;
  if (idx < 262144) { z1wbf[idx] = f2bf(z1w[idx]); return; }
  idx -= 262144;
  if (idx < 131072) {
    int o = idx >> 8, k = idx & 255;
    wcatbf[idx] = f2bf(o < 256 ? Ur[o * 256 + k] : U[(o - 256) * 256 + k]);
    return;
  }
  idx -= 131072;
  if (idx < 196608) { nmbf[idx] = f2bf(nmw[idx]); return; }
  idx -= 196608;
  if (idx < 262144) { pmbf[idx] = f2bf(pm[idx]); return; }
  idx -= 262144;
  if (idx < 262144) { qbf[idx] = f2bf(qs[idx]); return; }
}

// ---------------------------------------------------------------------------
// Phase B: FWr[b,h] = facts[b]·Wr[h] + Wr_b[h] + Ur_b[h];  FW[b,h] = facts[b]·W[h] + W_b[h]
// fp32, block handles 4 rows, thread = output h.
// ---------------------------------------------------------------------------
__global__ __launch_bounds__(256) void fact_proj(
    const float* __restrict__ facts, const float* __restrict__ Wr, const float* __restrict__ Wrb,
    const float* __restrict__ Urb, const float* __restrict__ Ww, const float* __restrict__ Wb,
    float* __restrict__ FWr, float* __restrict__ FW) {
  __shared__ float fl[4][HH];
  const int b0 = blockIdx.x * 4;
  const int tid = threadIdx.x;
#pragma unroll
  for (int r = 0; r < 4; ++r) fl[r][tid] = facts[(b0 + r) * HH + tid];
  __syncthreads();
  float ar[4] = {0.f, 0.f, 0.f, 0.f}, aw[4] = {0.f, 0.f, 0.f, 0.f};
  const float4* wr = (const float4*)(Wr + tid * HH);
  const float4* ww = (const float4*)(Ww + tid * HH);
  for (int d4 = 0; d4 < 64; ++d4) {
    float4 a = wr[d4], b = ww[d4];
#pragma unroll
    for (int r = 0; r < 4; ++r) {
      float4 f = *(const float4*)&fl[r][d4 * 4];  // LDS broadcast
      ar[r] += a.x * f.x + a.y * f.y + a.z * f.z + a.w * f.w;
      aw[r] += b.x * f.x + b.y * f.y + b.z * f.z + b.w * f.w;
    }
  }
  const float br = Wrb[tid] + Urb[tid], bw = Wb[tid];
#pragma unroll
  for (int r = 0; r < 4; ++r) {
    FWr[(b0 + r) * HH + tid] = ar[r] + br;
    FW[(b0 + r) * HH + tid] = aw[r] + bw;
  }
}

// ---------------------------------------------------------------------------
// Phase A: gate GEMM. Block = (n, 2 i's) -> 128 rows (2i x 64j) x 256 k, K=1024.
// z built on the fly into LDS (bf16), z1_w^T fragments loaded direct from L2.
// Fused tanh + z2_w reduction -> G[n,i,j].
// K-order: for h-chunk hc (8 x 32), sections s=0..3; B d-index = s*256 + hc*32 + kk.
// ---------------------------------------------------------------------------
__global__ __launch_bounds__(512, 2) void gate_gemm(
    const float* __restrict__ facts, const float* __restrict__ prevM,
    const float* __restrict__ questions, const unsigned short* __restrict__ z1wbf,
    const float* __restrict__ z1b, const float* __restrict__ z2w,
    const float* __restrict__ z2b, float* __restrict__ G) {
  __shared__ unsigned short A[128][136];  // stride 136 (68 words, 4 mod 32 -> 2-way max)
  __shared__ float Gpart[128][4];
  const int bi = blockIdx.x;
  const int n = bi >> 5, i0 = (bi & 31) * 2;
  const int tid = threadIdx.x;
  const int w = tid >> 6, l = tid & 63;
  const int rg = w >> 2, cg = w & 3;        // rowgroup (i-local), colgroup
  const int l15 = l & 15, q = l >> 4;
  const int hh2 = (tid & 15) * 2, jb = tid >> 4;  // builder mapping

  const float* fn = facts + n * SS * HH;
  const float* qn = questions + (n * SS + i0) * HH;
  const float* mn = prevM + (n * SS + i0) * HH;

  const f32x4 zero4 = {0.f, 0.f, 0.f, 0.f};
  f32x4 acc[4][4];
#pragma unroll
  for (int a = 0; a < 4; ++a)
#pragma unroll
    for (int b = 0; b < 4; ++b) acc[a][b] = zero4;

  float2 fv0, fv1, qv0, qv1, mv0, mv1;
  auto prefetch = [&](int hc) {
    const int h = hc * 32 + hh2;
    fv0 = *(const float2*)(fn + jb * HH + h);
    fv1 = *(const float2*)(fn + (jb + 32) * HH + h);
    qv0 = *(const float2*)(qn + h);
    qv1 = *(const float2*)(qn + HH + h);
    mv0 = *(const float2*)(mn + h);
    mv1 = *(const float2*)(mn + HH + h);
  };
  prefetch(0);

  for (int hc = 0; hc < 8; ++hc) {
    // B fragments for this h-chunk (z1_w bf16 is L2-resident; 16B/lane loads)
    short8 Bf[4][4];
    const unsigned short* bb = z1wbf + (cg * 64 + l15) * 1024 + hc * 32 + q * 8;
#pragma unroll
    for (int s = 0; s < 4; ++s)
#pragma unroll
      for (int nf = 0; nf < 4; ++nf)
        Bf[s][nf] = *(const short8*)(bb + (nf * 16) * 1024 + s * 256);

    // build A-tile from prefetched registers
    {
      float2 fl2[2] = {fv0, fv1}, ql2[2] = {qv0, qv1}, ml2[2] = {mv0, mv1};
#pragma unroll
      for (int pl = 0; pl < 2; ++pl) {
        const int j = jb + pl * 32;
#pragma unroll
        for (int il = 0; il < 2; ++il) {
          const int row = il * 64 + j;
          const float fx = fl2[pl].x, fy = fl2[pl].y;
          const float qx = ql2[il].x, qy = ql2[il].y;
          const float mx = ml2[il].x, my = ml2[il].y;
          *(unsigned int*)&A[row][0 * 32 + hh2] = pk2(fx * qx, fy * qy);
          *(unsigned int*)&A[row][1 * 32 + hh2] = pk2(fx * mx, fy * my);
          *(unsigned int*)&A[row][2 * 32 + hh2] = pk2(fabsf(fx - qx), fabsf(fy - qy));
          *(unsigned int*)&A[row][3 * 32 + hh2] = pk2(fabsf(fx - mx), fabsf(fy - my));
        }
      }
    }
    if (hc < 7) prefetch(hc + 1);
    __syncthreads();

#pragma unroll
    for (int s = 0; s < 4; ++s) {
      short8 Af[4];
#pragma unroll
      for (int mf = 0; mf < 4; ++mf)
        Af[mf] = *(const short8*)&A[rg * 64 + mf * 16 + l15][s * 32 + q * 8];
#pragma unroll
      for (int mf = 0; mf < 4; ++mf)
#pragma unroll
        for (int nf = 0; nf < 4; ++nf)
          acc[mf][nf] = __builtin_amdgcn_mfma_f32_16x16x32_bf16(Af[mf], Bf[s][nf], acc[mf][nf], 0, 0, 0);
    }
    __syncthreads();
  }

  // epilogue: tanh, scale by z2_w, reduce over k
  float psum[4][4];
#pragma unroll
  for (int mf = 0; mf < 4; ++mf)
#pragma unroll
    for (int v = 0; v < 4; ++v) psum[mf][v] = 0.f;

#pragma unroll
  for (int nf = 0; nf < 4; ++nf) {
    const int k = cg * 64 + nf * 16 + l15;
    const float zb = z1b[k], zw = z2w[k];
#pragma unroll
    for (int mf = 0; mf < 4; ++mf)
#pragma unroll
      for (int v = 0; v < 4; ++v) {
        const float x = acc[mf][nf][v] + zb;
        const float e = __expf(2.f * x);
        const float t = 1.f - 2.f / (e + 1.f);  // tanh(x)
        psum[mf][v] += zw * t;
      }
  }
#pragma unroll
  for (int d = 1; d < 16; d <<= 1)
#pragma unroll
    for (int mf = 0; mf < 4; ++mf)
#pragma unroll
      for (int v = 0; v < 4; ++v) psum[mf][v] += __shfl_xor(psum[mf][v], d, 64);
  if (l15 == 0) {
#pragma unroll
    for (int mf = 0; mf < 4; ++mf)
#pragma unroll
      for (int v = 0; v < 4; ++v)
        Gpart[rg * 64 + mf * 16 + q * 4 + v][cg] = psum[mf][v];
  }
  __syncthreads();
  if (tid < 128) {
    const float g = Gpart[tid][0] + Gpart[tid][1] + Gpart[tid][2] + Gpart[tid][3] + z2b[0];
    const int i = i0 + (tid >> 6), j = tid & 63;
    G[(n * SS + i) * SS + j] = g;
  }
}

// ---------------------------------------------------------------------------
// Phase A2: masked softmax over j. One wave per (n,i); lane = j.
// ---------------------------------------------------------------------------
__global__ void softmax_attn(const float* __restrict__ G, const int* __restrict__ doc_len,
                             float* __restrict__ attn) {
  const int gid = blockIdx.x * 256 + threadIdx.x;
  const int wid = gid >> 6, l = gid & 63;
  const int n = wid >> 6, i = wid & 63;
  const int dl = doc_len[n];
  const float g = G[(n * SS + i) * SS + l];
  const float x = (l < dl && g != 0.0f) ? g : -INFINITY;  // matches where(G*mask==0,-inf)
  float mx = x;
#pragma unroll
  for (int d = 1; d < 64; d <<= 1) mx = fmaxf(mx, __shfl_xor(mx, d, 64));
  const float e = (x == -INFINITY) ? 0.f : __expf(x - mx);
  float s = e;
#pragma unroll
  for (int d = 1; d < 64; d <<= 1) s += __shfl_xor(s, d, 64);
  attn[(n * SS + i) * SS + l] = e / s;
}

// ---------------------------------------------------------------------------
// Phase C: GRU-style scan. Block = (n, 16 i-rows), 512 threads (8 waves).
// RESTRUCTURED: wave w owns h in [32w, 32w+32) for BOTH the Ur (r-gate) and U
// (candidate) projections, so the elementwise update runs entirely in-register
// on the MFMA accumulators. The fp32 master state lives in registers (8/lane).
// Only the bf16 C broadcast copy goes through LDS, double-buffered -> ONE
// barrier per step (was 2) and no Y/Cf LDS round-trips (190KB -> ~72KB/step).
// FWr/FW are per-lane scalar loads software-pipelined one step ahead.
// ---------------------------------------------------------------------------
__global__ __launch_bounds__(512, 2) void gru_scan(
    const unsigned short* __restrict__ wcat, const float* __restrict__ FWr,
    const float* __restrict__ FW, const float* __restrict__ Ub,
    const float* __restrict__ attn, unsigned short* __restrict__ Cout) {
  __shared__ unsigned short Cbf[2][16 * 264];  // bf16 C, stride 264 (132 dw, 4 mod 32)
  __shared__ float attn_sT[64 * 16];           // transposed: [t][row] -> b128 broadcast

  const int bi = blockIdx.x, n = bi >> 2, i0 = (bi & 3) * 16;
  const int tid = threadIdx.x, w = tid >> 6, l = tid & 63;
  const int l15 = l & 15, q = l >> 4;
  const int h0 = w * 32 + l15;  // this lane's first h column (second is h0+16)

  // persistent B-fragments: f=0/1 -> Ur cols h0/h0+16 ; f=2/3 -> U cols h0/h0+16
  short8 Bf[8][4];
#pragma unroll
  for (int f = 0; f < 4; ++f) {
    const int wrow = ((f >> 1) ? 256 : 0) + w * 32 + (f & 1) * 16 + l15;
    const unsigned short* bb = wcat + wrow * 256 + q * 8;
#pragma unroll
    for (int kt = 0; kt < 8; ++kt)
      Bf[kt][f] = *(const short8*)(bb + kt * 32);
  }

  const float ub0 = Ub[h0], ub1 = Ub[h0 + 16];

  // attn transposed into LDS; zero C buffer 0
  for (int e = tid; e < 64 * 16; e += 512)
    attn_sT[e] = attn[(n * SS + i0 + (e & 15)) * SS + (e >> 4)];
  for (int e = tid; e < 16 * 132; e += 512) ((unsigned int*)Cbf[0])[e] = 0u;
  __syncthreads();

  const float* fwr_g = FWr + n * SS * HH;
  const float* fw_g  = FW + n * SS * HH;

  // fp32 master state in registers: rows q*4+v, cols h0 (idx 0) and h0+16 (idx 1)
  float cm[2][4];
#pragma unroll
  for (int a = 0; a < 2; ++a)
#pragma unroll
    for (int v = 0; v < 4; ++v) cm[a][v] = 0.f;

  // pipelined fact-projection scalars (t = 0)
  float fr0 = fwr_g[h0], fr1 = fwr_g[h0 + 16];
  float fc0 = fw_g[h0],  fc1 = fw_g[h0 + 16];

  for (int t = 0; t < 64; ++t) {
    const unsigned short* Cr = Cbf[t & 1];
    unsigned short* Cw = Cbf[(t & 1) ^ 1];

    // A-fragments: full C tile (rows = l15, k-slices)
    short8 Af[8];
#pragma unroll
    for (int kt = 0; kt < 8; ++kt)
      Af[kt] = *(const short8*)&Cr[l15 * 264 + kt * 32 + q * 8];

    // prefetch next step's FWr/FW (consumed next iteration -> latency hidden)
    float nr0 = 0.f, nr1 = 0.f, nc0 = 0.f, nc1 = 0.f;
    if (t < 63) {
      nr0 = fwr_g[(t + 1) * HH + h0];
      nr1 = fwr_g[(t + 1) * HH + h0 + 16];
      nc0 = fw_g[(t + 1) * HH + h0];
      nc1 = fw_g[(t + 1) * HH + h0 + 16];
    }

    f32x4 acc[4];
    const f32x4 z4 = {0.f, 0.f, 0.f, 0.f};
#pragma unroll
    for (int f = 0; f < 4; ++f) acc[f] = z4;
#pragma unroll
    for (int kt = 0; kt < 8; ++kt)
#pragma unroll
      for (int f = 0; f < 4; ++f)
        acc[f] = __builtin_amdgcn_mfma_f32_16x16x32_bf16(Af[kt], Bf[kt][f], acc[f], 0, 0, 0);

    // gates for this lane's 4 rows (broadcast read, 16B)
    const f32x4 gv = *(const f32x4*)&attn_sT[t * 16 + q * 4];

    // in-register GRU update; write only bf16 C to the other buffer
#pragma unroll
    for (int v = 0; v < 4; ++v) {
      const int row = q * 4 + v;
      const float g = gv[v];
      {  // h = h0
        const float r = 1.f / (1.f + __expf(-(fr0 + acc[0][v])));
        const float u = acc[2][v] + ub0;
        const float xx = fc0 + r * u;
        const float eh = __expf(2.f * xx);
        const float ht = 1.f - 2.f / (eh + 1.f);
        cm[0][v] = g * ht + (1.f - g) * cm[0][v];
        Cw[row * 264 + h0] = f2bf(cm[0][v]);
      }
      {  // h = h0 + 16
        const float r = 1.f / (1.f + __expf(-(fr1 + acc[1][v])));
        const float u = acc[3][v] + ub1;
        const float xx = fc1 + r * u;
        const float eh = __expf(2.f * xx);
        const float ht = 1.f - 2.f / (eh + 1.f);
        cm[1][v] = g * ht + (1.f - g) * cm[1][v];
        Cw[row * 264 + h0 + 16] = f2bf(cm[1][v]);
      }
    }
    fr0 = nr0; fr1 = nr1; fc0 = nc0; fc1 = nc1;
    __syncthreads();  // single barrier: Cw complete before next step's Af reads
  }

  // final C is in buffer 0 (t=63 wrote Cbf[0]); write bf16 for phase D
  for (int e = tid; e < 16 * 128; e += 512) {
    const int row = e >> 7, wo = e & 127;
    ((unsigned int*)Cout)[(n * SS + i0 + row) * 128 + wo] =
        *(const unsigned int*)&Cbf[0][row * 264 + wo * 2];
  }
}

// ---------------------------------------------------------------------------
// Phase D: next_mem = relu([prevM | C | questions] @ nm_w^T + nm_b)
// Block tile 64 rows x 64 cols, K=768 (sections of 256). 4 waves, M=16 each.
// ---------------------------------------------------------------------------
__global__ __launch_bounds__(256) void next_mem_gemm(
    const unsigned short* __restrict__ pmbf, const unsigned short* __restrict__ cbf,
    const unsigned short* __restrict__ qbf, const unsigned short* __restrict__ nmbf,
    const float* __restrict__ nmb, float* __restrict__ out) {
  __shared__ unsigned short A[64][40];  // stride 40 bf16 (20 words -> 2-way max)
  const int bi = blockIdx.x;
  const int rb = bi >> 2, cb = bi & 3;
  const int r0 = rb * 64, c0 = cb * 64;
  const int tid = threadIdx.x, w = tid >> 6, l = tid & 63;
  const int l15 = l & 15, q = l >> 4;

  f32x4 acc[4];
  const f32x4 z4 = {0.f, 0.f, 0.f, 0.f};
#pragma unroll
  for (int nf = 0; nf < 4; ++nf) acc[nf] = z4;

  for (int kt = 0; kt < 24; ++kt) {
    const int kg = kt * 32;
    const unsigned short* src =
        kg < 256 ? (pmbf + kg) : (kg < 512 ? (cbf + kg - 256) : (qbf + kg - 512));
    const int kk = (tid & 15) * 2;
#pragma unroll
    for (int ps = 0; ps < 4; ++ps) {
      const int row = ps * 16 + (tid >> 4);
      *(unsigned int*)&A[row][kk] = *(const unsigned int*)(src + (r0 + row) * HH + kk);
    }
    __syncthreads();
    short8 Bfr[4];
#pragma unroll
    for (int nf = 0; nf < 4; ++nf)
      Bfr[nf] = *(const short8*)(nmbf + (c0 + nf * 16 + l15) * 768 + kg + q * 8);
    const short8 Af = *(const short8*)&A[w * 16 + l15][q * 8];
#pragma unroll
    for (int nf = 0; nf < 4; ++nf)
      acc[nf] = __builtin_amdgcn_mfma_f32_16x16x32_bf16(Af, Bfr[nf], acc[nf], 0, 0, 0);
    __syncthreads();
  }
#pragma unroll
  for (int nf = 0; nf < 4; ++nf) {
    const int col = c0 + nf * 16 + l15;
    const float bv = nmb[col];
#pragma unroll
    for (int v = 0; v < 4; ++v) {
      const int grow = r0 + w * 16 + q * 4 + v;
      out[grow * HH + col] = fmaxf(acc[nf][v] + bv, 0.f);
    }
  }
}

// ---------------------------------------------------------------------------
extern "C" void kernel_launch(void* const* d_in, const int* in_sizes, int n_in,
                              void* d_out, int out_size, void* d_ws, size_t ws_size,
                              hipStream_t stream) {
  const float* facts     = (const float*)d_in[0];
  const float* prevM     = (const float*)d_in[1];
  const float* questions = (const float*)d_in[2];
  const int*   doc_len   = (const int*)d_in[3];
  const float* z1w = (const float*)d_in[4];
  const float* z1b = (const float*)d_in[5];
  const float* z2w = (const float*)d_in[6];
  const float* z2b = (const float*)d_in[7];
  const float* Wrw = (const float*)d_in[8];
  const float* Wrb = (const float*)d_in[9];
  const float* Urw = (const float*)d_in[10];
  const float* Urb = (const float*)d_in[11];
  const float* Ww  = (const float*)d_in[12];
  const float* Wb  = (const float*)d_in[13];
  const float* Uw  = (const float*)d_in[14];
  const float* Ub  = (const float*)d_in[15];
  const float* nmw = (const float*)d_in[16];
  const float* nmb = (const float*)d_in[17];

  char* ws = (char*)d_ws;
  unsigned short* z1wbf  = (unsigned short*)(ws + 0);        // 512 KB
  unsigned short* wcatbf = (unsigned short*)(ws + 524288);   // 256 KB
  unsigned short* nmbf   = (unsigned short*)(ws + 786432);   // 384 KB
  unsigned short* pmbf   = (unsigned short*)(ws + 1179648);  // 512 KB
  unsigned short* qbf    = (unsigned short*)(ws + 1703936);  // 512 KB
  float* G   = (float*)(ws + 2228224);                       // 256 KB
  float* FWr = (float*)(ws + 2490368);                       // 1 MB
  float* FW  = (float*)(ws + 3538944);                       // 1 MB
  unsigned short* cbf = (unsigned short*)(ws + 4587520);     // 512 KB  (total ~4.9 MB)

  float* out  = (float*)d_out;
  float* attn = out + NB * SS * HH;  // second output region

  prolog_cvt<<<4352, 256, 0, stream>>>(z1w, Urw, Uw, nmw, prevM, questions,
                                       z1wbf, wcatbf, nmbf, pmbf, qbf);
  fact_proj<<<256, 256, 0, stream>>>(facts, Wrw, Wrb, Urb, Ww, Wb, FWr, FW);
  gate_gemm<<<512, 512, 0, stream>>>(facts, prevM, questions, z1wbf, z1b, z2w, z2b, G);
  softmax_attn<<<256, 256, 0, stream>>>(G, doc_len, attn);
  gru_scan<<<64, 512, 0, stream>>>(wcatbf, FWr, FW, Ub, attn, cbf);
  next_mem_gemm<<<64, 256, 0, stream>>>(pmbf, cbf, qbf, nmbf, nmb, out);
}